// Round 7
// baseline (20089.281 us; speedup 1.0000x reference)
//
#include <hip/hip_runtime.h>

typedef unsigned short u16;
typedef unsigned int u32;
typedef float v2f __attribute__((ext_vector_type(2)));

#define NT 1024
#define Bv 32
#define Tv 256
#define Wv 128
#define Rv 4
#define Nv 128
#define DELTAv 1e-6f

__device__ __forceinline__ float bf2f(u16 u){
  union { u32 i; float f; } c; c.i = ((u32)u) << 16; return c.f;
}
__device__ __forceinline__ u16 f2bf(float f){
  union { float f; u32 u; } c; c.f = f;
  u32 u = c.u;
  return (u16)((u + 0x7fffu + ((u >> 16) & 1u)) >> 16);
}
__device__ __forceinline__ float sigm(float x){ return 1.0f / (1.0f + __expf(-x)); }
__device__ __forceinline__ float softplusf(float x){ return fmaxf(x, 0.f) + log1pf(__expf(-fabsf(x))); }
__device__ __forceinline__ float wredsum(float v){
  #pragma unroll
  for (int o = 32; o > 0; o >>= 1) v += __shfl_down(v, o, 64);
  return v;
}
__device__ __forceinline__ float wredmax(float v){
  #pragma unroll
  for (int o = 32; o > 0; o >>= 1) v = fmaxf(v, __shfl_down(v, o, 64));
  return v;
}
__device__ __forceinline__ float ldval(const void* p, int idx, int dt32){
  return dt32 ? ((const float*)p)[idx] : bf2f(((const u16*)p)[idx]);
}

// 8-deep register double-buffered GEMV partial: sum_k wp[k*STRIDE] . x[2k..2k+1]
template<int ITERS, int STRIDE>
__device__ __forceinline__ float gemv_f2(const float2* __restrict__ wp, const float* __restrict__ xp){
  v2f acc = (v2f)(0.f);
  v2f wb[8], wn[8];
  #pragma unroll
  for (int i = 0; i < 8; i++){ float2 t = wp[i * STRIDE]; wb[i] = (v2f){t.x, t.y}; }
  #pragma unroll 1
  for (int c = 0; c < ITERS - 8; c += 8){
    #pragma unroll
    for (int i = 0; i < 8; i++){ float2 t = wp[(c + 8 + i) * STRIDE]; wn[i] = (v2f){t.x, t.y}; }
    #pragma unroll
    for (int i = 0; i < 8; i++){
      v2f x2 = *(const v2f*)(xp + 2 * (c + i));
      acc += wb[i] * x2;
      wb[i] = wn[i];
    }
  }
  #pragma unroll
  for (int i = 0; i < 8; i++){
    v2f x2 = *(const v2f*)(xp + 2 * (ITERS - 8 + i));
    acc += wb[i] * x2;
  }
  return acc.x + acc.y;
}

// ---- dtype detect (flag=1 -> fp32 tensors, 0 -> bf16) ----
__global__ void detect_dtype(const u16* __restrict__ buf, int* __restrict__ flag){
  int lane = threadIdx.x;
  float crazy = 0.f;
  for (int i = 0; i < 4; i++){
    u16 v = buf[lane * 4 + i];
    int e = (v >> 7) & 0xFF;
    if (e != 0 && (e < 117 || e > 137)) crazy += 1.f;
  }
  crazy = wredsum(crazy);
  if (lane == 0) flag[0] = (crazy >= 32.f) ? 1 : 0;
}

__device__ __forceinline__ float rdsrc(const void* s, size_t idx, int f32){
  return f32 ? ((const float*)s)[idx] : bf2f(((const u16*)s)[idx]);
}

// identity-column pack to float2: dst[k2*Jd + j] = (W[j][2k2], W[j][2k2+1])
__global__ void pack_w(const void* __restrict__ src, float2* __restrict__ dst,
                       int Js, int Jd, int K, const int* __restrict__ flag){
  int j = blockIdx.x * 256 + threadIdx.x;
  int k2 = blockIdx.y;
  if (j >= Jd) return;
  float2 o = make_float2(0.f, 0.f);
  if (j < Js){
    o.x = rdsrc(src, (size_t)j * K + 2 * k2, flag[0]);
    o.y = rdsrc(src, (size_t)j * K + 2 * k2 + 1, flag[0]);
  }
  dst[(size_t)k2 * Jd + j] = o;
}

__device__ __forceinline__ int permctl(int c){
  // packed ctl col -> original interleaved col: [hE(128); rv r-major(512)]
  if (c < 128) return 5 * c;
  int q = c - 128; return 5 * (q & 127) + 1 + (q >> 7);
}
__device__ __forceinline__ int permout(int c){
  // packed out col -> original col: [h(128); rv r-major(512)]
  if (c < 128) return c;
  int q = c - 128; return 128 + 4 * (q & 127) + (q >> 7);
}

__global__ void pack_ctl(const void* __restrict__ src, float2* __restrict__ dst,
                         const int* __restrict__ flag){
  int j = blockIdx.x * 256 + threadIdx.x;
  int k2 = blockIdx.y;
  if (j >= 512) return;
  float2 o;
  o.x = rdsrc(src, (size_t)j * 640 + permctl(2 * k2), flag[0]);
  o.y = rdsrc(src, (size_t)j * 640 + permctl(2 * k2 + 1), flag[0]);
  dst[(size_t)k2 * 512 + j] = o;
}

__global__ void pack_out(const void* __restrict__ src, float2* __restrict__ dst,
                         const int* __restrict__ flag){
  int j = threadIdx.x;
  int k2 = blockIdx.y;
  if (j >= 128) return;
  float2 o;
  o.x = rdsrc(src, (size_t)j * 640 + permout(2 * k2), flag[0]);
  o.y = rdsrc(src, (size_t)j * 640 + permout(2 * k2 + 1), flag[0]);
  dst[(size_t)k2 * 128 + j] = o;
}

__global__ void fill_half(u16* __restrict__ p, int n){
  int i = blockIdx.x * 256 + threadIdx.x;
  if (i < n) p[i] = 0x3F00;
}

__global__ __launch_bounds__(NT) void dnc_main(
    const void* __restrict__ input,
    const void* __restrict__ enc_bih_g, const void* __restrict__ enc_bhh_g,
    const void* __restrict__ ctl_bih_g, const void* __restrict__ ctl_bhh_g,
    const void* __restrict__ iface_b_g, const void* __restrict__ out_b_g,
    const float2* __restrict__ encPW, const float2* __restrict__ ctlPW,
    const float2* __restrict__ ifPW, const float2* __restrict__ outPW,
    void* __restrict__ outp, const int* __restrict__ dtflag)
{
  const int bid = blockIdx.x;   // owner batch
  const int tid = threadIdx.x;
  const int lane = tid & 63;
  const int wid = tid >> 6;
  const int dt32 = dtflag[0];

  __shared__ __align__(16) float memS[Nv * 129];   // 66048 B
  __shared__ __align__(16) float linkS[Nv * 129];  // 66048 B
  __shared__ __align__(16) float pp[NT];           // ctl partials / xi / fw+bw
  __shared__ __align__(16) float ppE[NT];          // enc partials / out partials
  __shared__ __align__(16) float xhC[768];   // [hE(128); rv r-major(512); hC(128)]
  __shared__ __align__(16) float xinS[128];
  __shared__ __align__(16) float rkeyS[512], rwS[512], rcS[512];
  __shared__ __align__(16) float wkeyS[128], eraseS[128], wvecS[128];
  __shared__ __align__(16) float wwS[128], usageS[128], precS[128], wcS[128];
  __shared__ __align__(16) float uS[128], sortedU[128], scanA[128], alS[128], sqS[128];
  __shared__ __align__(16) float encBias[512], ctlBias[512];
  __shared__ __align__(16) float outBias[128];
  __shared__ float rstrS[4], fgS[4], rmRaw[12], rmS[12], scal[8];

  const int wE = (tid >= 919) ? (tid - 919) : (tid < 23 ? 105 + tid : -1);
  float cE = 0.f;
  float cC = 0.f;

  // ---- init ----
  if (tid < 512){
    encBias[tid] = ldval(enc_bih_g, tid, dt32) + ldval(enc_bhh_g, tid, dt32);
    ctlBias[tid] = ldval(ctl_bih_g, tid, dt32) + ldval(ctl_bhh_g, tid, dt32);
    rwS[tid] = 0.f;
  }
  if (tid < 768) xhC[tid] = 0.f;
  if (tid < 128){
    outBias[tid] = ldval(out_b_g, tid, dt32);
    wwS[tid] = 0.f; usageS[tid] = 0.f; precS[tid] = 0.f;
  }
  for (int i = tid; i < Nv * 129; i += NT){ memS[i] = 0.f; linkS[i] = 0.f; }
  if (tid < 64){
    int idx = (bid * Tv + 0) * Wv + 2 * tid;
    xinS[2 * tid] = ldval(input, idx, dt32);
    xinS[2 * tid + 1] = ldval(input, idx + 1, dt32);
  }
  __syncthreads();

  // ---- preamble: encoder step 0 ----
  if (tid >= 512){
    int o = tid - 512;
    ppE[o] = gemv_f2<64, 512>(encPW + o, xinS);   // hE=0 -> Whh part zero
  }
  __syncthreads();
  if (wE >= 0){
    float g0 = ppE[wE] + encBias[wE];
    float g1 = ppE[128 + wE] + encBias[128 + wE];
    float g2 = ppE[256 + wE] + encBias[256 + wE];
    float g3 = ppE[384 + wE] + encBias[384 + wE];
    float cn = sigm(g1) * cE + sigm(g0) * tanhf(g2);
    cE = cn;
    xhC[wE] = sigm(g3) * tanhf(cn);   // hE(0)
  }
  if (tid >= 64 && tid < 128){
    int w2 = (tid - 64) * 2;
    int idx = (bid * Tv + 1) * Wv + w2;
    xinS[w2] = ldval(input, idx, dt32);
    xinS[w2 + 1] = ldval(input, idx + 1, dt32);
  }
  __syncthreads();

  // =========================== main loop ===========================
  for (int t = 0; t < Tv; ++t){
    // Ph1: store out(t-1) (tid<128) + ctl gates GEMV (all)
    if (t > 0 && tid < 128){
      float o = outBias[tid];
      #pragma unroll
      for (int s = 0; s < 8; s++) o += ppE[s * 128 + tid];
      size_t oi = ((size_t)bid * Tv + (t - 1)) * Wv + tid;
      if (dt32) ((float*)outp)[oi] = o;
      else ((u16*)outp)[oi] = f2bf(o);
    }
    {
      int s = tid >> 9, o = tid & 511;
      pp[tid] = gemv_f2<192, 512>(ctlPW + (s * 192) * 512 + o, xhC + s * 384);
    }
    __syncthreads();

    // Ph2: ctl pointwise (tid<128) || enc gates(t+1) GEMV (tid>=512)
    if (tid < 128){
      float g0 = pp[tid] + pp[512 + tid] + ctlBias[tid];
      float g1 = pp[128 + tid] + pp[640 + tid] + ctlBias[128 + tid];
      float g2 = pp[256 + tid] + pp[768 + tid] + ctlBias[256 + tid];
      float g3 = pp[384 + tid] + pp[896 + tid] + ctlBias[384 + tid];
      float cn = sigm(g1) * cC + sigm(g0) * tanhf(g2);
      cC = cn;
      xhC[640 + tid] = sigm(g3) * tanhf(cn);   // hC(t)
    } else if (tid >= 512){
      int o = tid - 512;
      ppE[o] = gemv_f2<64, 512>(encPW + o, xinS)
             + gemv_f2<64, 512>(encPW + 64 * 512 + o, xhC);
    }
    __syncthreads();

    // Ph3: iface GEMV (tid<919) || enc pointwise -> hE(t+1)
    if (tid < 919){
      pp[tid] = ldval(iface_b_g, tid, dt32) + gemv_f2<64, 928>(ifPW + tid, xhC + 640);
    }
    if (wE >= 0){
      float g0 = ppE[wE] + encBias[wE];
      float g1 = ppE[128 + wE] + encBias[128 + wE];
      float g2 = ppE[256 + wE] + encBias[256 + wE];
      float g3 = ppE[384 + wE] + encBias[384 + wE];
      float cn = sigm(g1) * cE + sigm(g0) * tanhf(g2);
      cE = cn;
      xhC[wE] = sigm(g3) * tanhf(cn);   // hE(t+1)
    }
    __syncthreads();

    // Ph4: parse xi || stage x(t+2)
    if (tid < 919){
      float v = pp[tid];
      if (tid < 512) rkeyS[tid] = tanhf(v);
      else if (tid < 516) rstrS[tid - 512] = softplusf(v);
      else if (tid < 644) wkeyS[tid - 516] = tanhf(v);
      else if (tid == 644) scal[0] = softplusf(v);
      else if (tid < 773) eraseS[tid - 645] = sigm(v);
      else if (tid < 901) wvecS[tid - 773] = tanhf(v);
      else if (tid < 905) fgS[tid - 901] = sigm(v);
      else if (tid == 905) scal[1] = sigm(v);
      else if (tid == 906) scal[2] = sigm(v);
      else rmRaw[tid - 907] = v;
    } else if (tid >= 928 && tid < 992){
      int w2 = (tid - 928) * 2;
      int col = (t + 2 < Tv) ? t + 2 : Tv - 1;
      int idx = (bid * Tv + col) * Wv + w2;
      xinS[w2] = ldval(input, idx, dt32);
      xinS[w2 + 1] = ldval(input, idx + 1, dt32);
    }
    __syncthreads();

    // Ph5: key norms (waves 0-4) || usage+uS (waves 5-6) || rm softmax (w7) || old-mem sq (waves 8-9)
    if (wid < 5){
      float* arr = (wid < 4) ? (rkeyS + wid * 128) : wkeyS;
      float a = arr[lane], bq = arr[lane + 64];
      float s = wredsum(a * a + bq * bq);
      s = __shfl(s, 0, 64);
      float inv = 1.0f / (sqrtf(s) + DELTAv);
      arr[lane] = a * inv; arr[lane + 64] = bq * inv;
    } else if (wid < 7){
      int n = (wid - 5) * 64 + lane;
      float us = usageS[n];
      us = us + (1.f - us) * wwS[n];
      float ret = (1.f - fgS[0] * rwS[n]) * (1.f - fgS[1] * rwS[128 + n]) *
                  (1.f - fgS[2] * rwS[256 + n]) * (1.f - fgS[3] * rwS[384 + n]);
      us *= ret;
      usageS[n] = us;
      uS[n] = DELTAv + (1.f - DELTAv) * us;
    } else if (tid >= 448 && tid < 452){
      int r = tid - 448;
      float m0 = rmRaw[3 * r], m1 = rmRaw[3 * r + 1], m2 = rmRaw[3 * r + 2];
      float mx = fmaxf(m0, fmaxf(m1, m2));
      float e0 = __expf(m0 - mx), e1 = __expf(m1 - mx), e2 = __expf(m2 - mx);
      float s = e0 + e1 + e2;
      rmS[3 * r] = e0 / s; rmS[3 * r + 1] = e1 / s; rmS[3 * r + 2] = e2 / s;
    } else if (wid >= 8 && wid < 10){
      int n = (wid - 8) * 64 + lane;
      float sq = 0.f;
      #pragma unroll 8
      for (int j = 0; j < 128; j++){
        float m = memS[n * 129 + j];
        sq = fmaf(m, m, sq);
      }
      sqS[n] = sq;
    }
    __syncthreads();

    // Ph6: write-content scores (old mem; dot only, sq precomputed)
    if (tid < 128){
      float dt = 0.f;
      #pragma unroll 8
      for (int j = 0; j < 128; j++) dt = fmaf(memS[tid * 129 + j], wkeyS[j], dt);
      wcS[tid] = dt / (sqrtf(sqS[tid]) + DELTAv) * scal[0];
    }
    __syncthreads();

    // Ph7: wc softmax (wave 0) || rank+scan+alloc (wave 1, same-wave LDS scatter)
    if (wid == 0){
      float a = wcS[lane], bq = wcS[lane + 64];
      float mx = wredmax(fmaxf(a, bq)); mx = __shfl(mx, 0, 64);
      float ea = __expf(a - mx), eb = __expf(bq - mx);
      float s = wredsum(ea + eb); s = __shfl(s, 0, 64);
      wcS[lane] = ea / s; wcS[lane + 64] = eb / s;
    } else if (wid == 1){
      int l = lane;
      float u0 = uS[l], u1 = uS[64 + l];
      int r0 = 0, r1 = 0;
      for (int m = 0; m < 128; m++){
        float um = uS[m];
        r0 += (um < u0) || (um == u0 && m < l);
        r1 += (um < u1) || (um == u1 && m < 64 + l);
      }
      sortedU[r0] = u0; sortedU[r1] = u1;
      float a = sortedU[2 * l], bq = sortedU[2 * l + 1];   // same-wave RAW: compiler orders via lgkmcnt
      float p = a * bq;
      float incl = p;
      #pragma unroll
      for (int o = 1; o < 64; o <<= 1){
        float tv = __shfl_up(incl, o, 64);
        if (l >= o) incl *= tv;
      }
      float exh = __shfl_up(incl, 1, 64);
      if (l == 0) exh = 1.f;
      scanA[2 * l] = exh;          // exclusive prod at sorted pos 2l
      scanA[2 * l + 1] = exh * a;  // at pos 2l+1
      float ex0 = scanA[r0], ex1 = scanA[r1];
      alS[l] = (1.f - u0) * ex0;
      alS[64 + l] = (1.f - u1) * ex1;
    }
    __syncthreads();

    // Ph8: write weighting + sum (wave 0, 2/lane)
    if (wid == 0){
      float w0v = scal[2] * (scal[1] * alS[lane] + (1.f - scal[1]) * wcS[lane]);
      float w1v = scal[2] * (scal[1] * alS[64 + lane] + (1.f - scal[1]) * wcS[64 + lane]);
      wwS[lane] = w0v; wwS[64 + lane] = w1v;
      float s = wredsum(w0v + w1v);
      if (lane == 0) scal[3] = s;
    }
    __syncthreads();

    // Ph9: mem erase/write + link update (old prec), all LDS
    #pragma unroll
    for (int it = 0; it < 16; it++){
      int e = it * NT + tid;
      int n = e >> 7, w = e & 127;
      float wwn = wwS[n];
      float m = memS[n * 129 + w];
      memS[n * 129 + w] = m * (1.f - wwn * eraseS[w]) + wwn * wvecS[w];
      float l = linkS[n * 129 + w];
      linkS[n * 129 + w] = (n == w) ? 0.f
        : ((1.f - wwn - wwS[w]) * l + wwn * precS[w]);
    }
    __syncthreads();

    // Ph10: read-content dots (0-127) || prec (128-255) || fw (256-767) || bw (768-1023, 2 outs)
    if (tid < 128){
      float sq = 0.f, d0 = 0.f, d1 = 0.f, d2 = 0.f, d3 = 0.f;
      #pragma unroll 4
      for (int j = 0; j < 128; j++){
        float m = memS[tid * 129 + j];
        sq = fmaf(m, m, sq);
        d0 = fmaf(m, rkeyS[j], d0);
        d1 = fmaf(m, rkeyS[128 + j], d1);
        d2 = fmaf(m, rkeyS[256 + j], d2);
        d3 = fmaf(m, rkeyS[384 + j], d3);
      }
      float inv = 1.f / (sqrtf(sq) + DELTAv);
      rcS[tid]       = d0 * inv * rstrS[0];
      rcS[128 + tid] = d1 * inv * rstrS[1];
      rcS[256 + tid] = d2 * inv * rstrS[2];
      rcS[384 + tid] = d3 * inv * rstrS[3];
    } else if (tid < 256){
      int n = tid - 128;
      precS[n] = (1.f - scal[3]) * precS[n] + wwS[n];
    } else if (tid < 768){
      int o = tid - 256, r = o >> 7, i = o & 127;
      const float* rwp = rwS + r * 128;
      float acc = 0.f;
      #pragma unroll 8
      for (int j = 0; j < 128; j++) acc = fmaf(rwp[j], linkS[i * 129 + j], acc);
      pp[o] = acc;   // fw
    } else {
      int o2 = tid - 768, i = o2 & 127;
      int r1 = o2 >> 7, r2 = r1 + 2;
      const float* rw1 = rwS + r1 * 128;
      const float* rw2 = rwS + r2 * 128;
      float accA = 0.f, accB = 0.f;
      #pragma unroll 8
      for (int j = 0; j < 128; j++){
        float l = linkS[j * 129 + i];
        accA = fmaf(rw1[j], l, accA);
        accB = fmaf(rw2[j], l, accB);
      }
      pp[512 + o2] = accA;        // bw outputs 0..255
      pp[512 + o2 + 256] = accB;  // bw outputs 256..511
    }
    __syncthreads();

    // Ph11: rc softmax + new rw (wave r handles head r)
    if (wid < 4){
      int r = wid;
      float a = rcS[r * 128 + lane], bq = rcS[r * 128 + 64 + lane];
      float mx = wredmax(fmaxf(a, bq)); mx = __shfl(mx, 0, 64);
      float ea = __expf(a - mx), eb = __expf(bq - mx);
      float s = wredsum(ea + eb); s = __shfl(s, 0, 64);
      float pa = ea / s, pb = eb / s;
      int o0 = r * 128 + lane, o1 = o0 + 64;
      rwS[o0] = rmS[3 * r] * pp[512 + o0] + rmS[3 * r + 1] * pp[o0] + rmS[3 * r + 2] * pa;
      rwS[o1] = rmS[3 * r] * pp[512 + o1] + rmS[3 * r + 1] * pp[o1] + rmS[3 * r + 2] * pb;
    }
    __syncthreads();

    // Ph12: rv full-K (tid<512 -> xhC) || out-GEMV h-part (tid>=512 -> ppE[512..1023])
    if (tid < 512){
      int r = tid >> 7, w = tid & 127;
      const float* rwp = rwS + r * 128;
      float acc = 0.f;
      #pragma unroll 8
      for (int n = 0; n < 128; n++) acc = fmaf(rwp[n], memS[n * 129 + w], acc);
      xhC[128 + tid] = acc;
    } else {
      int s = (tid - 512) >> 7, j = tid & 127;
      ppE[tid] = gemv_f2<16, 128>(outPW + (s * 16) * 128 + j, xhC + 640 + 32 * s);
    }
    __syncthreads();

    // Ph13: out-GEMV rv-part (tid<512 -> ppE[0..511])
    if (tid < 512){
      int s = tid >> 7, j = tid & 127;
      ppE[tid] = gemv_f2<64, 128>(outPW + (64 + s * 64) * 128 + j, xhC + 128 + 128 * s);
    }
    __syncthreads();
  }

  // final output store (t = Tv-1)
  if (tid < 128){
    float o = outBias[tid];
    #pragma unroll
    for (int s = 0; s < 8; s++) o += ppE[s * 128 + tid];
    size_t oi = ((size_t)bid * Tv + (Tv - 1)) * Wv + tid;
    if (dt32) ((float*)outp)[oi] = o;
    else ((u16*)outp)[oi] = f2bf(o);
  }
}

extern "C" void kernel_launch(void* const* d_in, const int* in_sizes, int n_in,
                              void* d_out, int out_size, void* d_ws, size_t ws_size,
                              hipStream_t stream) {
  (void)in_sizes; (void)n_in;
  const void* input   = d_in[0];
  const void* enc_Wih = d_in[2];
  const void* enc_Whh = d_in[3];
  const void* enc_bih = d_in[4];
  const void* enc_bhh = d_in[5];
  const void* ctl_Wih = d_in[6];
  const void* ctl_Whh = d_in[7];
  const void* ctl_bih = d_in[8];
  const void* ctl_bhh = d_in[9];
  const void* iface_W = d_in[10];
  const void* iface_b = d_in[11];
  const void* out_W   = d_in[12];
  const void* out_b   = d_in[13];

  char* ws = (char*)d_ws;
  size_t off = 0;
  int* dtflag = (int*)(ws + off); off += 256;
  float2* encPW = (float2*)(ws + off); off += (size_t)128 * 512 * 8;   // [Wih k2 0..64 | Whh 64..128]
  float2* ctlPW = (float2*)(ws + off); off += (size_t)384 * 512 * 8;   // [perm Wih 0..320 | Whh 320..384]
  float2* ifPW  = (float2*)(ws + off); off += (size_t)64 * 928 * 8;
  float2* outPW = (float2*)(ws + off); off += (size_t)320 * 128 * 8;
  const size_t need_bytes = off;   // ~2.9 MB

  if (ws_size < need_bytes){
    fill_half<<<dim3((out_size + 255) / 256), dim3(256), 0, stream>>>((u16*)d_out, out_size);
    return;
  }

  detect_dtype<<<dim3(1), dim3(64), 0, stream>>>((const u16*)input, dtflag);

  pack_w<<<dim3(2, 64), 256, 0, stream>>>(enc_Wih, encPW, 512, 512, 128, dtflag);
  pack_w<<<dim3(2, 64), 256, 0, stream>>>(enc_Whh, encPW + 64 * 512, 512, 512, 128, dtflag);
  pack_ctl<<<dim3(2, 320), 256, 0, stream>>>(ctl_Wih, ctlPW, dtflag);
  pack_w<<<dim3(2, 64), 256, 0, stream>>>(ctl_Whh, ctlPW + 320 * 512, 512, 512, 128, dtflag);
  pack_w<<<dim3(4, 64), 256, 0, stream>>>(iface_W, ifPW, 919, 928, 128, dtflag);
  pack_out<<<dim3(1, 320), 128, 0, stream>>>(out_W, outPW, dtflag);

  dnc_main<<<dim3(Bv), dim3(NT), 0, stream>>>(
      input, enc_bih, enc_bhh, ctl_bih, ctl_bhh, iface_b, out_b,
      encPW, ctlPW, ifPW, outPW, d_out, dtflag);
}

// Round 8
// 10667.220 us; speedup vs baseline: 1.8833x; 1.8833x over previous
//
#include <hip/hip_runtime.h>

typedef unsigned short u16;
typedef unsigned int u32;

#define NT 1024
#define Bv 32
#define Tv 256
#define Wv 128
#define Rv 4
#define Nv 128
#define DELTAv 1e-6f

__device__ __forceinline__ float bf2f(u16 u){
  union { u32 i; float f; } c; c.i = ((u32)u) << 16; return c.f;
}
__device__ __forceinline__ u16 f2bf(float f){
  union { float f; u32 u; } c; c.f = f;
  u32 u = c.u;
  return (u16)((u + 0x7fffu + ((u >> 16) & 1u)) >> 16);
}
__device__ __forceinline__ void unp(u32 v, float& a, float& b){
  union { u32 i; float f; } c0, c1;
  c0.i = v << 16; c1.i = v & 0xffff0000u;
  a = c0.f; b = c1.f;
}
__device__ __forceinline__ float sigm(float x){ return 1.0f / (1.0f + __expf(-x)); }
__device__ __forceinline__ float softplusf(float x){ return fmaxf(x, 0.f) + log1pf(__expf(-fabsf(x))); }
__device__ __forceinline__ float wredsum(float v){
  #pragma unroll
  for (int o = 32; o > 0; o >>= 1) v += __shfl_down(v, o, 64);
  return v;
}
__device__ __forceinline__ float wredmax(float v){
  #pragma unroll
  for (int o = 32; o > 0; o >>= 1) v = fmaxf(v, __shfl_down(v, o, 64));
  return v;
}
__device__ __forceinline__ float ldval(const void* p, int idx, int dt32){
  return dt32 ? ((const float*)p)[idx] : bf2f(((const u16*)p)[idx]);
}

// 8-deep register double-buffered GEMV partial over bf16-pair weights:
// sum_k unpack(wp[k*STRIDE]) . x[2k..2k+1]
template<int ITERS, int STRIDE>
__device__ __forceinline__ float gemv_bf(const u32* __restrict__ wp, const float* __restrict__ xp){
  float a0 = 0.f, a1 = 0.f;
  u32 wb[8];
  #pragma unroll
  for (int i = 0; i < 8; i++) wb[i] = wp[i * STRIDE];
  #pragma unroll 1
  for (int c = 0; c < ITERS - 8; c += 8){
    u32 wn[8];
    #pragma unroll
    for (int i = 0; i < 8; i++) wn[i] = wp[(c + 8 + i) * STRIDE];
    #pragma unroll
    for (int i = 0; i < 8; i++){
      float w0, w1; unp(wb[i], w0, w1);
      float2 x2 = *(const float2*)(xp + 2 * (c + i));
      a0 = fmaf(x2.x, w0, a0); a1 = fmaf(x2.y, w1, a1);
      wb[i] = wn[i];
    }
  }
  #pragma unroll
  for (int i = 0; i < 8; i++){
    float w0, w1; unp(wb[i], w0, w1);
    float2 x2 = *(const float2*)(xp + 2 * (ITERS - 8 + i));
    a0 = fmaf(x2.x, w0, a0); a1 = fmaf(x2.y, w1, a1);
  }
  return a0 + a1;
}

// ---- dtype detect (flag=1 -> fp32 tensors, 0 -> bf16) ----
__global__ void detect_dtype(const u16* __restrict__ buf, int* __restrict__ flag){
  int lane = threadIdx.x;
  float crazy = 0.f;
  for (int i = 0; i < 4; i++){
    u16 v = buf[lane * 4 + i];
    int e = (v >> 7) & 0xFF;
    if (e != 0 && (e < 117 || e > 137)) crazy += 1.f;
  }
  crazy = wredsum(crazy);
  if (lane == 0) flag[0] = (crazy >= 32.f) ? 1 : 0;
}

__device__ __forceinline__ u16 rdbf(const void* s, size_t idx, int f32){
  return f32 ? f2bf(((const float*)s)[idx]) : ((const u16*)s)[idx];
}

// identity-column pack: dst[k2*Jd + j] = bf16pair(W[j][2k2], W[j][2k2+1])
__global__ void pack_w(const void* __restrict__ src, u32* __restrict__ dst,
                       int Js, int Jd, int K, const int* __restrict__ flag){
  int j = blockIdx.x * 256 + threadIdx.x;
  int k2 = blockIdx.y;
  if (j >= Jd) return;
  u16 lo = 0, hi = 0;
  if (j < Js){
    lo = rdbf(src, (size_t)j * K + 2 * k2, flag[0]);
    hi = rdbf(src, (size_t)j * K + 2 * k2 + 1, flag[0]);
  }
  dst[(size_t)k2 * Jd + j] = (u32)lo | ((u32)hi << 16);
}

__device__ __forceinline__ int permctl(int c){
  // packed ctl col -> original interleaved col: [hE(128); rv r-major(512)]
  if (c < 128) return 5 * c;
  int q = c - 128; return 5 * (q & 127) + 1 + (q >> 7);
}
__device__ __forceinline__ int permout(int c){
  // packed out col -> original col: [h(128); rv r-major(512)]
  if (c < 128) return c;
  int q = c - 128; return 128 + 4 * (q & 127) + (q >> 7);
}

__global__ void pack_ctl(const void* __restrict__ src, u32* __restrict__ dst,
                         const int* __restrict__ flag){
  int j = blockIdx.x * 256 + threadIdx.x;
  int k2 = blockIdx.y;
  if (j >= 512) return;
  u16 lo = rdbf(src, (size_t)j * 640 + permctl(2 * k2), flag[0]);
  u16 hi = rdbf(src, (size_t)j * 640 + permctl(2 * k2 + 1), flag[0]);
  dst[(size_t)k2 * 512 + j] = (u32)lo | ((u32)hi << 16);
}

__global__ void pack_out(const void* __restrict__ src, u32* __restrict__ dst,
                         const int* __restrict__ flag){
  int j = threadIdx.x;
  int k2 = blockIdx.y;
  if (j >= 128) return;
  u16 lo = rdbf(src, (size_t)j * 640 + permout(2 * k2), flag[0]);
  u16 hi = rdbf(src, (size_t)j * 640 + permout(2 * k2 + 1), flag[0]);
  dst[(size_t)k2 * 128 + j] = (u32)lo | ((u32)hi << 16);
}

__global__ void fill_half(u16* __restrict__ p, int n){
  int i = blockIdx.x * 256 + threadIdx.x;
  if (i < n) p[i] = 0x3F00;
}

__global__ __launch_bounds__(NT) void dnc_main(
    const void* __restrict__ input,
    const void* __restrict__ enc_bih_g, const void* __restrict__ enc_bhh_g,
    const void* __restrict__ ctl_bih_g, const void* __restrict__ ctl_bhh_g,
    const void* __restrict__ iface_b_g, const void* __restrict__ out_b_g,
    const u32* __restrict__ encPW, const u32* __restrict__ ctlPW,
    const u32* __restrict__ ifPW, const u32* __restrict__ outPW,
    void* __restrict__ outp, const int* __restrict__ dtflag)
{
  const int bid = blockIdx.x;   // owner batch
  const int tid = threadIdx.x;
  const int lane = tid & 63;
  const int wid = tid >> 6;
  const int dt32 = dtflag[0];

  __shared__ __align__(16) float memS[Nv * 129];   // 66048 B
  __shared__ __align__(16) float linkS[Nv * 129];  // 66048 B
  __shared__ __align__(16) float pp[NT];           // ctl partials / xi / fw+bw
  __shared__ __align__(16) float ppE[NT];          // enc partials / out partials
  __shared__ __align__(16) float xhC[768];   // [hE(128); rv r-major(512); hC(128)]
  __shared__ __align__(16) float xinS[128];
  __shared__ __align__(16) float rkeyS[512], rwS[512], rcS[512];
  __shared__ __align__(16) float wkeyS[128], eraseS[128], wvecS[128];
  __shared__ __align__(16) float wwS[128], usageS[128], precS[128], wcS[128];
  __shared__ __align__(16) float uS[128], sortedU[128], scanA[128], alS[128], sqS[128];
  __shared__ __align__(16) float encBias[512], ctlBias[512];
  __shared__ __align__(16) float outBias[128];
  __shared__ float rstrS[4], fgS[4], rmRaw[12], rmS[12], scal[8];

  const int wE = (tid >= 919) ? (tid - 919) : (tid < 23 ? 105 + tid : -1);
  float cE = 0.f;
  float cC = 0.f;

  // ---- init ----
  if (tid < 512){
    encBias[tid] = ldval(enc_bih_g, tid, dt32) + ldval(enc_bhh_g, tid, dt32);
    ctlBias[tid] = ldval(ctl_bih_g, tid, dt32) + ldval(ctl_bhh_g, tid, dt32);
    rwS[tid] = 0.f;
  }
  if (tid < 768) xhC[tid] = 0.f;
  if (tid < 128){
    outBias[tid] = ldval(out_b_g, tid, dt32);
    wwS[tid] = 0.f; usageS[tid] = 0.f; precS[tid] = 0.f;
  }
  for (int i = tid; i < Nv * 129; i += NT){ memS[i] = 0.f; linkS[i] = 0.f; }
  if (tid < 64){
    int idx = (bid * Tv + 0) * Wv + 2 * tid;
    xinS[2 * tid] = ldval(input, idx, dt32);
    xinS[2 * tid + 1] = ldval(input, idx + 1, dt32);
  }
  __syncthreads();

  // ---- preamble: encoder step 0 ----
  if (tid >= 512){
    int o = tid - 512;
    ppE[o] = gemv_bf<64, 512>(encPW + o, xinS);   // hE=0 -> Whh part zero
  }
  __syncthreads();
  if (wE >= 0){
    float g0 = ppE[wE] + encBias[wE];
    float g1 = ppE[128 + wE] + encBias[128 + wE];
    float g2 = ppE[256 + wE] + encBias[256 + wE];
    float g3 = ppE[384 + wE] + encBias[384 + wE];
    float cn = sigm(g1) * cE + sigm(g0) * tanhf(g2);
    cE = cn;
    xhC[wE] = sigm(g3) * tanhf(cn);   // hE(0)
  }
  if (tid >= 64 && tid < 128){
    int w2 = (tid - 64) * 2;
    int idx = (bid * Tv + 1) * Wv + w2;
    xinS[w2] = ldval(input, idx, dt32);
    xinS[w2 + 1] = ldval(input, idx + 1, dt32);
  }
  __syncthreads();

  // =========================== main loop ===========================
  for (int t = 0; t < Tv; ++t){
    // Ph1: store out(t-1) (tid<128) + ctl gates GEMV (all)
    if (t > 0 && tid < 128){
      float o = outBias[tid];
      #pragma unroll
      for (int s = 0; s < 8; s++) o += ppE[s * 128 + tid];
      size_t oi = ((size_t)bid * Tv + (t - 1)) * Wv + tid;
      if (dt32) ((float*)outp)[oi] = o;
      else ((u16*)outp)[oi] = f2bf(o);
    }
    {
      int s = tid >> 9, o = tid & 511;
      pp[tid] = gemv_bf<192, 512>(ctlPW + (s * 192) * 512 + o, xhC + s * 384);
    }
    __syncthreads();

    // Ph2: ctl pointwise (tid<128) || enc gates(t+1) GEMV (tid>=512)
    if (tid < 128){
      float g0 = pp[tid] + pp[512 + tid] + ctlBias[tid];
      float g1 = pp[128 + tid] + pp[640 + tid] + ctlBias[128 + tid];
      float g2 = pp[256 + tid] + pp[768 + tid] + ctlBias[256 + tid];
      float g3 = pp[384 + tid] + pp[896 + tid] + ctlBias[384 + tid];
      float cn = sigm(g1) * cC + sigm(g0) * tanhf(g2);
      cC = cn;
      xhC[640 + tid] = sigm(g3) * tanhf(cn);   // hC(t)
    } else if (tid >= 512){
      int o = tid - 512;
      ppE[o] = gemv_bf<64, 512>(encPW + o, xinS)
             + gemv_bf<64, 512>(encPW + 64 * 512 + o, xhC);
    }
    __syncthreads();

    // Ph3: iface GEMV (tid<919) || enc pointwise -> hE(t+1)
    if (tid < 919){
      pp[tid] = ldval(iface_b_g, tid, dt32) + gemv_bf<64, 928>(ifPW + tid, xhC + 640);
    }
    if (wE >= 0){
      float g0 = ppE[wE] + encBias[wE];
      float g1 = ppE[128 + wE] + encBias[128 + wE];
      float g2 = ppE[256 + wE] + encBias[256 + wE];
      float g3 = ppE[384 + wE] + encBias[384 + wE];
      float cn = sigm(g1) * cE + sigm(g0) * tanhf(g2);
      cE = cn;
      xhC[wE] = sigm(g3) * tanhf(cn);   // hE(t+1)
    }
    __syncthreads();

    // Ph4: parse xi || stage x(t+2)
    if (tid < 919){
      float v = pp[tid];
      if (tid < 512) rkeyS[tid] = tanhf(v);
      else if (tid < 516) rstrS[tid - 512] = softplusf(v);
      else if (tid < 644) wkeyS[tid - 516] = tanhf(v);
      else if (tid == 644) scal[0] = softplusf(v);
      else if (tid < 773) eraseS[tid - 645] = sigm(v);
      else if (tid < 901) wvecS[tid - 773] = tanhf(v);
      else if (tid < 905) fgS[tid - 901] = sigm(v);
      else if (tid == 905) scal[1] = sigm(v);
      else if (tid == 906) scal[2] = sigm(v);
      else rmRaw[tid - 907] = v;
    } else if (tid >= 928 && tid < 992){
      int w2 = (tid - 928) * 2;
      int col = (t + 2 < Tv) ? t + 2 : Tv - 1;
      int idx = (bid * Tv + col) * Wv + w2;
      xinS[w2] = ldval(input, idx, dt32);
      xinS[w2 + 1] = ldval(input, idx + 1, dt32);
    }
    __syncthreads();

    // Ph5: key norms (waves 0-4) || usage+uS (waves 5-6) || rm softmax (w7) || old-mem sq (waves 8-9)
    if (wid < 5){
      float* arr = (wid < 4) ? (rkeyS + wid * 128) : wkeyS;
      float a = arr[lane], bq = arr[lane + 64];
      float s = wredsum(a * a + bq * bq);
      s = __shfl(s, 0, 64);
      float inv = 1.0f / (sqrtf(s) + DELTAv);
      arr[lane] = a * inv; arr[lane + 64] = bq * inv;
    } else if (wid < 7){
      int n = (wid - 5) * 64 + lane;
      float us = usageS[n];
      us = us + (1.f - us) * wwS[n];
      float ret = (1.f - fgS[0] * rwS[n]) * (1.f - fgS[1] * rwS[128 + n]) *
                  (1.f - fgS[2] * rwS[256 + n]) * (1.f - fgS[3] * rwS[384 + n]);
      us *= ret;
      usageS[n] = us;
      uS[n] = DELTAv + (1.f - DELTAv) * us;
    } else if (tid >= 448 && tid < 452){
      int r = tid - 448;
      float m0 = rmRaw[3 * r], m1 = rmRaw[3 * r + 1], m2 = rmRaw[3 * r + 2];
      float mx = fmaxf(m0, fmaxf(m1, m2));
      float e0 = __expf(m0 - mx), e1 = __expf(m1 - mx), e2 = __expf(m2 - mx);
      float s = e0 + e1 + e2;
      rmS[3 * r] = e0 / s; rmS[3 * r + 1] = e1 / s; rmS[3 * r + 2] = e2 / s;
    } else if (wid >= 8 && wid < 10){
      int n = (wid - 8) * 64 + lane;
      float sq = 0.f;
      #pragma unroll 8
      for (int j = 0; j < 128; j++){
        float m = memS[n * 129 + j];
        sq = fmaf(m, m, sq);
      }
      sqS[n] = sq;
    }
    __syncthreads();

    // Ph6: write-content scores (old mem; dot only, sq precomputed)
    if (tid < 128){
      float dt = 0.f;
      #pragma unroll 8
      for (int j = 0; j < 128; j++) dt = fmaf(memS[tid * 129 + j], wkeyS[j], dt);
      wcS[tid] = dt / (sqrtf(sqS[tid]) + DELTAv) * scal[0];
    }
    __syncthreads();

    // Ph7: wc softmax (wave 0) || rank+scan+alloc (wave 1, same-wave LDS scatter)
    if (wid == 0){
      float a = wcS[lane], bq = wcS[lane + 64];
      float mx = wredmax(fmaxf(a, bq)); mx = __shfl(mx, 0, 64);
      float ea = __expf(a - mx), eb = __expf(bq - mx);
      float s = wredsum(ea + eb); s = __shfl(s, 0, 64);
      wcS[lane] = ea / s; wcS[lane + 64] = eb / s;
    } else if (wid == 1){
      int l = lane;
      float u0 = uS[l], u1 = uS[64 + l];
      int r0 = 0, r1 = 0;
      for (int m = 0; m < 128; m++){
        float um = uS[m];
        r0 += (um < u0) || (um == u0 && m < l);
        r1 += (um < u1) || (um == u1 && m < 64 + l);
      }
      sortedU[r0] = u0; sortedU[r1] = u1;
      float a = sortedU[2 * l], bq = sortedU[2 * l + 1];   // same-wave RAW ordered via lgkmcnt
      float p = a * bq;
      float incl = p;
      #pragma unroll
      for (int o = 1; o < 64; o <<= 1){
        float tv = __shfl_up(incl, o, 64);
        if (l >= o) incl *= tv;
      }
      float exh = __shfl_up(incl, 1, 64);
      if (l == 0) exh = 1.f;
      scanA[2 * l] = exh;          // exclusive prod at sorted pos 2l
      scanA[2 * l + 1] = exh * a;  // at pos 2l+1
      float ex0 = scanA[r0], ex1 = scanA[r1];
      alS[l] = (1.f - u0) * ex0;
      alS[64 + l] = (1.f - u1) * ex1;
    }
    __syncthreads();

    // Ph8: write weighting + sum (wave 0, 2/lane)
    if (wid == 0){
      float w0v = scal[2] * (scal[1] * alS[lane] + (1.f - scal[1]) * wcS[lane]);
      float w1v = scal[2] * (scal[1] * alS[64 + lane] + (1.f - scal[1]) * wcS[64 + lane]);
      wwS[lane] = w0v; wwS[64 + lane] = w1v;
      float s = wredsum(w0v + w1v);
      if (lane == 0) scal[3] = s;
    }
    __syncthreads();

    // Ph9: mem erase/write + link update (old prec), all LDS
    #pragma unroll
    for (int it = 0; it < 16; it++){
      int e = it * NT + tid;
      int n = e >> 7, w = e & 127;
      float wwn = wwS[n];
      float m = memS[n * 129 + w];
      memS[n * 129 + w] = m * (1.f - wwn * eraseS[w]) + wwn * wvecS[w];
      float l = linkS[n * 129 + w];
      linkS[n * 129 + w] = (n == w) ? 0.f
        : ((1.f - wwn - wwS[w]) * l + wwn * precS[w]);
    }
    __syncthreads();

    // Ph10: read-content dots (0-127) || prec (128-255) || fw (256-767) || bw (768-1023, 2 outs)
    if (tid < 128){
      float sq = 0.f, d0 = 0.f, d1 = 0.f, d2 = 0.f, d3 = 0.f;
      #pragma unroll 4
      for (int j = 0; j < 128; j++){
        float m = memS[tid * 129 + j];
        sq = fmaf(m, m, sq);
        d0 = fmaf(m, rkeyS[j], d0);
        d1 = fmaf(m, rkeyS[128 + j], d1);
        d2 = fmaf(m, rkeyS[256 + j], d2);
        d3 = fmaf(m, rkeyS[384 + j], d3);
      }
      float inv = 1.f / (sqrtf(sq) + DELTAv);
      rcS[tid]       = d0 * inv * rstrS[0];
      rcS[128 + tid] = d1 * inv * rstrS[1];
      rcS[256 + tid] = d2 * inv * rstrS[2];
      rcS[384 + tid] = d3 * inv * rstrS[3];
    } else if (tid < 256){
      int n = tid - 128;
      precS[n] = (1.f - scal[3]) * precS[n] + wwS[n];
    } else if (tid < 768){
      int o = tid - 256, r = o >> 7, i = o & 127;
      const float* rwp = rwS + r * 128;
      float acc = 0.f;
      #pragma unroll 8
      for (int j = 0; j < 128; j++) acc = fmaf(rwp[j], linkS[i * 129 + j], acc);
      pp[o] = acc;   // fw
    } else {
      int o2 = tid - 768, i = o2 & 127;
      int r1 = o2 >> 7, r2 = r1 + 2;
      const float* rw1 = rwS + r1 * 128;
      const float* rw2 = rwS + r2 * 128;
      float accA = 0.f, accB = 0.f;
      #pragma unroll 8
      for (int j = 0; j < 128; j++){
        float l = linkS[j * 129 + i];
        accA = fmaf(rw1[j], l, accA);
        accB = fmaf(rw2[j], l, accB);
      }
      pp[512 + o2] = accA;        // bw outputs 0..255
      pp[512 + o2 + 256] = accB;  // bw outputs 256..511
    }
    __syncthreads();

    // Ph11: rc softmax + new rw (wave r handles head r)
    if (wid < 4){
      int r = wid;
      float a = rcS[r * 128 + lane], bq = rcS[r * 128 + 64 + lane];
      float mx = wredmax(fmaxf(a, bq)); mx = __shfl(mx, 0, 64);
      float ea = __expf(a - mx), eb = __expf(bq - mx);
      float s = wredsum(ea + eb); s = __shfl(s, 0, 64);
      float pa = ea / s, pb = eb / s;
      int o0 = r * 128 + lane, o1 = o0 + 64;
      rwS[o0] = rmS[3 * r] * pp[512 + o0] + rmS[3 * r + 1] * pp[o0] + rmS[3 * r + 2] * pa;
      rwS[o1] = rmS[3 * r] * pp[512 + o1] + rmS[3 * r + 1] * pp[o1] + rmS[3 * r + 2] * pb;
    }
    __syncthreads();

    // Ph12: rv full-K (tid<512 -> xhC) || out-GEMV h-part (tid>=512 -> ppE[512..1023])
    if (tid < 512){
      int r = tid >> 7, w = tid & 127;
      const float* rwp = rwS + r * 128;
      float acc = 0.f;
      #pragma unroll 8
      for (int n = 0; n < 128; n++) acc = fmaf(rwp[n], memS[n * 129 + w], acc);
      xhC[128 + tid] = acc;
    } else {
      int s = (tid - 512) >> 7, j = tid & 127;
      ppE[tid] = gemv_bf<16, 128>(outPW + (s * 16) * 128 + j, xhC + 640 + 32 * s);
    }
    __syncthreads();

    // Ph13: out-GEMV rv-part (tid<512 -> ppE[0..511])
    if (tid < 512){
      int s = tid >> 7, j = tid & 127;
      ppE[tid] = gemv_bf<64, 128>(outPW + (64 + s * 64) * 128 + j, xhC + 128 + 128 * s);
    }
    __syncthreads();
  }

  // final output store (t = Tv-1)
  if (tid < 128){
    float o = outBias[tid];
    #pragma unroll
    for (int s = 0; s < 8; s++) o += ppE[s * 128 + tid];
    size_t oi = ((size_t)bid * Tv + (Tv - 1)) * Wv + tid;
    if (dt32) ((float*)outp)[oi] = o;
    else ((u16*)outp)[oi] = f2bf(o);
  }
}

extern "C" void kernel_launch(void* const* d_in, const int* in_sizes, int n_in,
                              void* d_out, int out_size, void* d_ws, size_t ws_size,
                              hipStream_t stream) {
  (void)in_sizes; (void)n_in;
  const void* input   = d_in[0];
  const void* enc_Wih = d_in[2];
  const void* enc_Whh = d_in[3];
  const void* enc_bih = d_in[4];
  const void* enc_bhh = d_in[5];
  const void* ctl_Wih = d_in[6];
  const void* ctl_Whh = d_in[7];
  const void* ctl_bih = d_in[8];
  const void* ctl_bhh = d_in[9];
  const void* iface_W = d_in[10];
  const void* iface_b = d_in[11];
  const void* out_W   = d_in[12];
  const void* out_b   = d_in[13];

  char* ws = (char*)d_ws;
  size_t off = 0;
  int* dtflag = (int*)(ws + off); off += 256;
  u32* encPW = (u32*)(ws + off); off += (size_t)128 * 512 * 4;   // [Wih k2 0..64 | Whh 64..128]
  u32* ctlPW = (u32*)(ws + off); off += (size_t)384 * 512 * 4;   // [perm Wih 0..320 | Whh 320..384]
  u32* ifPW  = (u32*)(ws + off); off += (size_t)64 * 928 * 4;
  u32* outPW = (u32*)(ws + off); off += (size_t)320 * 128 * 4;
  const size_t need_bytes = off;   // ~1.45 MB (L2-resident)

  if (ws_size < need_bytes){
    fill_half<<<dim3((out_size + 255) / 256), dim3(256), 0, stream>>>((u16*)d_out, out_size);
    return;
  }

  detect_dtype<<<dim3(1), dim3(64), 0, stream>>>((const u16*)input, dtflag);

  pack_w<<<dim3(2, 64), 256, 0, stream>>>(enc_Wih, encPW, 512, 512, 128, dtflag);
  pack_w<<<dim3(2, 64), 256, 0, stream>>>(enc_Whh, encPW + 64 * 512, 512, 512, 128, dtflag);
  pack_ctl<<<dim3(2, 320), 256, 0, stream>>>(ctl_Wih, ctlPW, dtflag);
  pack_w<<<dim3(2, 64), 256, 0, stream>>>(ctl_Whh, ctlPW + 320 * 512, 512, 512, 128, dtflag);
  pack_w<<<dim3(4, 64), 256, 0, stream>>>(iface_W, ifPW, 919, 928, 128, dtflag);
  pack_out<<<dim3(1, 320), 128, 0, stream>>>(out_W, outPW, dtflag);

  dnc_main<<<dim3(Bv), dim3(NT), 0, stream>>>(
      input, enc_bih, enc_bhh, ctl_bih, ctl_bhh, iface_b, out_b,
      encPW, ctlPW, ifPW, outPW, d_out, dtflag);
}